// Round 1
// baseline (111.240 us; speedup 1.0000x reference)
//
#include <hip/hip_runtime.h>
#include <math.h>

// Problem constants (B,S,D,V,C) = (32, 2048, 512, 32000, 2)
#define BB 32
#define SS 2048
#define DD 512
#define TW 16              // t's per wave in pass 1
#define NCHUNK 32          // SS / (4 waves * TW) partials per batch

// ---------------------------------------------------------------------------
// Pass 1: per (batch, chunk) block — online-softmax over this chunk's 64 t's.
// Each wave handles TW t's; lane holds dims [8*lane, 8*lane+8) of q/row/acc.
// Block-combines its 4 wave partials into one (m, l, acc[512]) partial.
// ---------------------------------------------------------------------------
__global__ __launch_bounds__(256) void attn_pass1(
    const int* __restrict__ tokens, const float* __restrict__ emb,
    float* __restrict__ pacc, float* __restrict__ pm, float* __restrict__ pl)
{
    const int b     = blockIdx.x;
    const int chunk = blockIdx.y;
    const int tid   = threadIdx.x;
    const int wave  = tid >> 6;
    const int lane  = tid & 63;

    // q = emb[tokens[b,0]]
    const int qtok = tokens[(size_t)b * SS];
    const float4* q4 = (const float4*)(emb + (size_t)qtok * DD);
    const float4 qa = q4[lane * 2];
    const float4 qb = q4[lane * 2 + 1];

    // This wave's 16 token ids live in lanes 0..15; broadcast via shfl.
    const int tbase = chunk * (4 * TW) + wave * TW;
    int mytok = 0;
    if (lane < TW) mytok = tokens[(size_t)b * SS + tbase + lane];

    float m = -INFINITY, l = 0.f;
    float a0=0.f,a1=0.f,a2=0.f,a3=0.f,a4=0.f,a5=0.f,a6=0.f,a7=0.f;

    // Prime the pipeline with t = tbase
    int tok0 = __shfl(mytok, 0);
    const float4* r4 = (const float4*)(emb + (size_t)tok0 * DD);
    float4 ra = r4[lane * 2];
    float4 rb = r4[lane * 2 + 1];

#pragma unroll
    for (int i = 0; i < TW; ++i) {
        // Prefetch next row while we compute on the current one
        float4 na = ra, nb = rb;
        if (i + 1 < TW) {
            int ntok = __shfl(mytok, i + 1);
            const float4* n4 = (const float4*)(emb + (size_t)ntok * DD);
            na = n4[lane * 2];
            nb = n4[lane * 2 + 1];
        }

        // s_t = q . row  (per-lane partial, then 64-lane butterfly reduce)
        float s = qa.x*ra.x + qa.y*ra.y + qa.z*ra.z + qa.w*ra.w
                + qb.x*rb.x + qb.y*rb.y + qb.z*rb.z + qb.w*rb.w;
#pragma unroll
        for (int off = 32; off > 0; off >>= 1)
            s += __shfl_xor(s, off);

        // Online softmax update (row still in registers — single global pass)
        float mn    = fmaxf(m, s);
        float alpha = expf(m - mn);   // expf(-inf) == 0 handles first iter
        float p     = expf(s - mn);
        l  = l * alpha + p;
        a0 = a0 * alpha + p * ra.x;  a1 = a1 * alpha + p * ra.y;
        a2 = a2 * alpha + p * ra.z;  a3 = a3 * alpha + p * ra.w;
        a4 = a4 * alpha + p * rb.x;  a5 = a5 * alpha + p * rb.y;
        a6 = a6 * alpha + p * rb.z;  a7 = a7 * alpha + p * rb.w;
        m  = mn;

        ra = na; rb = nb;
    }

    // --- combine the block's 4 wave partials in LDS ---
    __shared__ float smax[4], ssum[4];
    __shared__ float sacc[4 * DD];
    {
        float* dst = &sacc[wave * DD + lane * 8];
        dst[0]=a0; dst[1]=a1; dst[2]=a2; dst[3]=a3;
        dst[4]=a4; dst[5]=a5; dst[6]=a6; dst[7]=a7;
        if (lane == 0) { smax[wave] = m; ssum[wave] = l; }
    }
    __syncthreads();

    const float M  = fmaxf(fmaxf(smax[0], smax[1]), fmaxf(smax[2], smax[3]));
    const float e0 = expf(smax[0] - M), e1 = expf(smax[1] - M);
    const float e2 = expf(smax[2] - M), e3 = expf(smax[3] - M);

    if (tid == 0) {
        pm[b * NCHUNK + chunk] = M;
        pl[b * NCHUNK + chunk] = e0*ssum[0] + e1*ssum[1] + e2*ssum[2] + e3*ssum[3];
    }
#pragma unroll
    for (int d = tid; d < DD; d += 256) {
        float v = e0*sacc[0*DD + d] + e1*sacc[1*DD + d]
                + e2*sacc[2*DD + d] + e3*sacc[3*DD + d];
        pacc[((size_t)(b * NCHUNK + chunk)) * DD + d] = v;  // unnormalized
    }
}

// ---------------------------------------------------------------------------
// Pass 2: per-batch merge of NCHUNK partials + fused classifier head.
// ---------------------------------------------------------------------------
__global__ __launch_bounds__(256) void attn_merge(
    const float* __restrict__ pacc, const float* __restrict__ pm,
    const float* __restrict__ pl,   const float* __restrict__ cls_w,
    const float* __restrict__ cls_b, float* __restrict__ out)
{
    const int b   = blockIdx.x;
    const int tid = threadIdx.x;

    __shared__ float sm[NCHUNK], sl[NCHUNK];
    if (tid < NCHUNK) {
        sm[tid] = pm[b * NCHUNK + tid];
        sl[tid] = pl[b * NCHUNK + tid];
    }
    __syncthreads();

    float M = -INFINITY;
#pragma unroll
    for (int i = 0; i < NCHUNK; ++i) M = fmaxf(M, sm[i]);
    float e[NCHUNK];
    float L = 0.f;
#pragma unroll
    for (int i = 0; i < NCHUNK; ++i) { e[i] = expf(sm[i] - M); L += e[i] * sl[i]; }
    const float invL = 1.0f / L;

    // pooled[d] for d = tid, tid+256 ; fuse logits = pooled @ cls_w.T
    float part0 = 0.f, part1 = 0.f;
#pragma unroll
    for (int d = tid; d < DD; d += 256) {
        float v = 0.f;
#pragma unroll
        for (int i = 0; i < NCHUNK; ++i)
            v += e[i] * pacc[((size_t)(b * NCHUNK + i)) * DD + d];
        v *= invL;
        part0 += v * cls_w[d];        // class 0
        part1 += v * cls_w[DD + d];   // class 1
    }

    __shared__ float r0[256], r1[256];
    r0[tid] = part0; r1[tid] = part1;
    __syncthreads();
#pragma unroll
    for (int s2 = 128; s2 > 0; s2 >>= 1) {
        if (tid < s2) { r0[tid] += r0[tid + s2]; r1[tid] += r1[tid + s2]; }
        __syncthreads();
    }
    if (tid == 0) {
        out[b * 2 + 0] = r0[0] + cls_b[0];
        out[b * 2 + 1] = r1[0] + cls_b[1];
    }
}

// ---------------------------------------------------------------------------
extern "C" void kernel_launch(void* const* d_in, const int* in_sizes, int n_in,
                              void* d_out, int out_size, void* d_ws, size_t ws_size,
                              hipStream_t stream)
{
    const int*   tokens = (const int*)  d_in[0];   // (32, 2048)
    const float* emb    = (const float*)d_in[1];   // (32000, 512)
    const float* cls_w  = (const float*)d_in[2];   // (2, 512)
    const float* cls_b  = (const float*)d_in[3];   // (2,)
    float*       out    = (float*)d_out;           // (32, 2)

    // Workspace: pacc [B][NCHUNK][D] (2 MB) + pm/pl [B][NCHUNK]
    float* pacc = (float*)d_ws;
    float* pm   = pacc + (size_t)BB * NCHUNK * DD;
    float* pl   = pm   + (size_t)BB * NCHUNK;

    dim3 g1(BB, NCHUNK);
    attn_pass1<<<g1, 256, 0, stream>>>(tokens, emb, pacc, pm, pl);
    attn_merge<<<BB, 256, 0, stream>>>(pacc, pm, pl, cls_w, cls_b, out);
}